// Round 6
// baseline (317.367 us; speedup 1.0000x reference)
//
#include <hip/hip_runtime.h>
#include <hip/hip_bf16.h>

// Problem constants (all powers of two -> index math is shifts/masks)
#define B_   8
#define N_   16384
#define C_   128
#define OUT_ 256
#define E_   262144

// ws word layout (uint32 offsets). ws_size ~537 MB, we use ~40 MB.
//   [0,        16384)    : cnt[row]; memset 0 -> per-row edge count (may exceed 64)
//   [16384,    16448)    : ovf_cnt (word 16384) + pad; memset covers it
//   [16448,    540736)   : overflow (row,col) pairs - correctness path only
//   [540736,   1589312)  : tab: fixed-capacity col table, 64 slots/row (16384*64)
//   [1589312,  1605696)  : Wt bf16 [n][k] transposed weights (256x128)
//   [1605696,  9994304)  : x_bf bf16 copy of x (B*N*C shorts)
#define CNT_OFF  0u
#define OVFC_OFF 16384u
#define OVF_OFF  16448u
#define TAB_OFF  540736u
#define WT_OFF   1589312u
#define XBF_OFF  1605696u

typedef __attribute__((ext_vector_type(8))) short bf16x8; // 8 bf16 = 4 VGPRs
typedef __attribute__((ext_vector_type(4))) float f32x4;

__device__ __forceinline__ unsigned short f2bf(float f) { // RNE, no NaN inputs
  unsigned u = __float_as_uint(f);
  u += 0x7FFFu + ((u >> 16) & 1u);
  return (unsigned short)(u >> 16);
}
__device__ __forceinline__ float gelu_exact(float v) {
  return 0.5f * v * (1.0f + erff(v * 0.70710678118654752f));
}
__device__ __forceinline__ unsigned umin_(unsigned a, unsigned b) {
  return a < b ? a : b;
}

// ------------- kernel 1: fused x->bf16 | direct edge-table build | Wt prep ------
// Fixed-capacity table (64 slots/row) built in ONE edge pass with atomic cursors
// (the gather needs the col SET, not order). Overflow rows (P ~ 1e-14 at
// Poisson(16)) spill (row,col) pairs to a global list replayed later -> correct
// for ANY input. Per-block dtype detect: odd u32 words are int64-highs (==0) or
// int32 index values (nonzero w.h.p.); 256 samples/block -> P(wrong) ~ 0.
__global__ __launch_bounds__(256) void k_prep(const float* __restrict__ x,
                                              const unsigned* __restrict__ eidx,
                                              const float* __restrict__ W,
                                              unsigned* __restrict__ ws) {
  const unsigned bid = blockIdx.x, tid = threadIdx.x;
  if (bid < 16384u) { // ---- x fp32 -> bf16 packed (4,194,304 float4 slots)
    unsigned i = bid * 256u + tid;
    float4 v = ((const float4*)x)[i];
    uint2 o;
    o.x = (unsigned)f2bf(v.x) | ((unsigned)f2bf(v.y) << 16);
    o.y = (unsigned)f2bf(v.z) | ((unsigned)f2bf(v.w) << 16);
    ((uint2*)(ws + XBF_OFF))[i] = o;
  } else if (bid < 17408u) { // ---- edge-table build, one edge per thread
    __shared__ int flag32;
    if (tid == 0) flag32 = 0;
    __syncthreads();
    unsigned e = (bid - 16384u) * 256u + tid; // 0..262143
    if (eidx[2u * e + 1u] != 0u) flag32 = 1;  // benign race
    __syncthreads();
    int row, col;
    if (flag32) {
      row = (int)eidx[e];
      col = (int)eidx[e + E_];
    } else {
      const long long* p = (const long long*)eidx;
      row = (int)p[e];
      col = (int)p[e + E_];
    }
    unsigned pos = atomicAdd(ws + CNT_OFF + (unsigned)row, 1u);
    if (pos < 64u) {
      ws[TAB_OFF + ((unsigned)row << 6) + pos] = (unsigned)col;
    } else { // correctness-only spill
      unsigned o = atomicAdd(ws + OVFC_OFF, 1u);
      ws[OVF_OFF + 2u * o]      = (unsigned)row;
      ws[OVF_OFF + 2u * o + 1u] = (unsigned)col;
    }
  } else { // ---- W fp32 -> bf16 transposed (128 blocks)
    unsigned t = (bid - 17408u) * 256u + tid; // 0..32767
    unsigned n = t >> 7, k = t & 127u;
    ((unsigned short*)(ws + WT_OFF))[n * 128u + k] = f2bf(W[k * 256u + n]);
  }
}

// -------- kernel 2: FUSED gather-max -> (LDS transpose) -> MFMA gemm -> GELU ----
// R5 counters: nothing saturated (HBM 20%, Mfma 2.5%, VALU 48%, Occ 42%), FETCH
// 85 MB vs ~36 ideal -> gathers were NOT L2-resident (tab + out-write streams
// thrash the exactly-4MB x_bf slice), and occupancy was LDS-capped at 4 blk/CU.
// R6 fixes, all aimed at that one diagnosis:
//   * LDS halved to 17408 B (Wt staged in n-QUARTERS) -> 8 blk/CU, 32 waves/CU;
//     grid 2048 = exactly one co-resident generation (256 CU x 8).
//   * nontemporal OUT stores + nontemporal TAB/OVF loads -> streams bypass L2,
//     x_bf slice stays hot.
//   * per-row trip guards (not shared max) -> -22% redundant gather traffic.
//   * cnt[] hoisted to one vector load/wave; degrees via full-EXEC __shfl.
// EXEC discipline (R1 bug): every __shfl under wave-uniform control flow.
// Max trick: fmax on raw u32 (hi channel; garbage low mantissa can't flip a
// bf16-level compare) and on u<<16 (lo channel, exact). batch = blockIdx&7 ->
// per-XCD 4 MB x_bf slice under round-robin dispatch.
__global__ __launch_bounds__(256, 8) void k_ag(const uint4* __restrict__ xbf4,
                                               const unsigned* __restrict__ ws,
                                               const unsigned short* __restrict__ Wt,
                                               const float* __restrict__ bias,
                                               float* __restrict__ out) {
  __shared__ unsigned short sm[8704]; // 17408 B: 4 trans strips / one Wt quarter
  const unsigned bi = blockIdx.x;          // 2048 = 256 m-tiles x 8 batches
  const unsigned b  = bi & 7u;
  const unsigned mbase = (bi >> 3) << 6;   // 64-row m-tile
  const unsigned tid = threadIdx.x;
  const unsigned wv = tid >> 6;            // wave id: rows [wv*16, wv*16+16)
  const unsigned lane = tid & 63u;
  const unsigned g  = lane >> 4;           // edge subgroup 0..3
  const unsigned ln = lane & 15u;          // uint4 slot within a 128-ch row
  const uint4* xb = xbf4 + ((size_t)b << 18); // rows stride 16 uint4
  const unsigned wbase = mbase + (wv << 4);

  // one load covers all 16 row degrees for this wave (lanes 16+ hold dups)
  const unsigned cnt16 = ws[CNT_OFF + wbase + ln];

#define MAXU4(U, ml, mh)                                                    \
  mh[0] = fmaxf(mh[0], __uint_as_float((U).x));                             \
  ml[0] = fmaxf(ml[0], __uint_as_float((U).x << 16));                       \
  mh[1] = fmaxf(mh[1], __uint_as_float((U).y));                             \
  ml[1] = fmaxf(ml[1], __uint_as_float((U).y << 16));                       \
  mh[2] = fmaxf(mh[2], __uint_as_float((U).z));                             \
  ml[2] = fmaxf(ml[2], __uint_as_float((U).z << 16));                       \
  mh[3] = fmaxf(mh[3], __uint_as_float((U).w));                             \
  ml[3] = fmaxf(ml[3], __uint_as_float((U).w << 16));

  // ---- phase 1: gather-max, 2 rows per iteration, per-row trip guards ----
  for (unsigned i = 0u; i < 16u; i += 2u) {
    const unsigned ra = wbase + i, rb = ra + 1u;
    const unsigned dega = (unsigned)__shfl((int)cnt16, (int)i);        // uniform
    const unsigned degb = (unsigned)__shfl((int)cnt16, (int)(i + 1u)); // uniform
    const unsigned d64a = dega < 64u ? dega : 64u;
    const unsigned d64b = degb < 64u ? degb : 64u;
    const unsigned dm1a = d64a - 1u; // used only when d64a > 0
    const unsigned dm1b = d64b - 1u;
    // tab: read-once stream, shared by all 8 XCDs -> bypass L2 (L3 serves it)
    const unsigned cprea = __builtin_nontemporal_load(ws + TAB_OFF + (ra << 6) + lane);
    const unsigned cpreb = __builtin_nontemporal_load(ws + TAB_OFF + (rb << 6) + lane);
    const uint4 xwa = xb[((size_t)ra << 4) + ln]; // own-row x (epilogue operand)
    const uint4 xwb = xb[((size_t)rb << 4) + ln];

    float mloa[4], mhia[4], mlob[4], mhib[4];
#pragma unroll
    for (int r = 0; r < 4; ++r) {
      mloa[r] = -INFINITY; mhia[r] = -INFINITY;
      mlob[r] = -INFINITY; mhib[r] = -INFINITY;
    }

    const unsigned mx = d64a > d64b ? d64a : d64b;
    for (unsigned t = 0u; t < mx; t += 16u) {
      if (t < d64a) { // wave-uniform -> full-EXEC shuffles inside
        unsigned ca[4];
#pragma unroll
        for (int k = 0; k < 4; ++k)
          ca[k] = (unsigned)__shfl((int)cprea,
                                   (int)umin_(t + 4u * (unsigned)k + g, dm1a));
        uint4 ua[4];
#pragma unroll
        for (int k = 0; k < 4; ++k) ua[k] = xb[((size_t)ca[k] << 4) + ln];
#pragma unroll
        for (int k = 0; k < 4; ++k) { MAXU4(ua[k], mloa, mhia) }
      }
      if (t < d64b) { // wave-uniform
        unsigned cb[4];
#pragma unroll
        for (int k = 0; k < 4; ++k)
          cb[k] = (unsigned)__shfl((int)cpreb,
                                   (int)umin_(t + 4u * (unsigned)k + g, dm1b));
        uint4 ub[4];
#pragma unroll
        for (int k = 0; k < 4; ++k) ub[k] = xb[((size_t)cb[k] << 4) + ln];
#pragma unroll
        for (int k = 0; k < 4; ++k) { MAXU4(ub[k], mlob, mhib) }
      }
    }
    if ((dega > 64u) | (degb > 64u)) { // overflow replay: shuffle-free
      unsigned no = ws[OVFC_OFF];
      for (unsigned k2 = g; k2 < no; k2 += 4u) {
        unsigned rr = __builtin_nontemporal_load(ws + OVF_OFF + 2u * k2);
        if (rr == ra) {
          uint4 u = xb[((size_t)ws[OVF_OFF + 2u * k2 + 1u] << 4) + ln];
          MAXU4(u, mloa, mhia)
        } else if (rr == rb) {
          uint4 u = xb[((size_t)ws[OVF_OFF + 2u * k2 + 1u] << 4) + ln];
          MAXU4(u, mlob, mhib)
        }
      }
    }

    // reduce across the 4 edge-groups (full EXEC, reconverged)
#pragma unroll
    for (int r = 0; r < 4; ++r) {
      mloa[r] = fmaxf(mloa[r], __shfl_xor(mloa[r], 16, 64));
      mhia[r] = fmaxf(mhia[r], __shfl_xor(mhia[r], 16, 64));
      mloa[r] = fmaxf(mloa[r], __shfl_xor(mloa[r], 32, 64));
      mhia[r] = fmaxf(mhia[r], __shfl_xor(mhia[r], 32, 64));
      mlob[r] = fmaxf(mlob[r], __shfl_xor(mlob[r], 16, 64));
      mhib[r] = fmaxf(mhib[r], __shfl_xor(mhib[r], 16, 64));
      mlob[r] = fmaxf(mlob[r], __shfl_xor(mlob[r], 32, 64));
      mhib[r] = fmaxf(mhib[r], __shfl_xor(mhib[r], 32, 64));
    }

    if (g == 0u) { // write both rows' aggr bf16 to this wave's LDS strip
      const bool hasa = (dega != 0u), hasb = (degb != 0u);
      unsigned xva[4] = {xwa.x, xwa.y, xwa.z, xwa.w};
      unsigned xvb[4] = {xwb.x, xwb.y, xwb.z, xwb.w};
      unsigned oxa[4], oxb[4];
#pragma unroll
      for (int r = 0; r < 4; ++r) {
        float vloa = hasa ? mloa[r] : 0.0f;
        float vhia = hasa ? __uint_as_float(__float_as_uint(mhia[r]) & 0xFFFF0000u) : 0.0f;
        oxa[r] = (unsigned)f2bf(vloa - __uint_as_float(xva[r] << 16)) |
                 ((unsigned)f2bf(vhia - __uint_as_float(xva[r] & 0xFFFF0000u)) << 16);
        float vlob = hasb ? mlob[r] : 0.0f;
        float vhib = hasb ? __uint_as_float(__float_as_uint(mhib[r]) & 0xFFFF0000u) : 0.0f;
        oxb[r] = (unsigned)f2bf(vlob - __uint_as_float(xvb[r] << 16)) |
                 ((unsigned)f2bf(vhib - __uint_as_float(xvb[r] & 0xFFFF0000u)) << 16);
      }
      uint4 oa = {oxa[0], oxa[1], oxa[2], oxa[3]};
      uint4 ob = {oxb[0], oxb[1], oxb[2], oxb[3]};
      *(uint4*)&sm[wv * 2176u + i * 136u + ln * 8u]        = oa;
      *(uint4*)&sm[wv * 2176u + (i + 1u) * 136u + ln * 8u] = ob;
    }
  }
#undef MAXU4

  __syncthreads(); // trans strips complete (also orders vs af reads)

  // ---- phase 2: A-fragments from LDS. lane(ln,q): A[m=ln][ch=kc*32+q*8..+8]
  const unsigned q = g;
  bf16x8 af[4];
#pragma unroll
  for (int kc = 0; kc < 4; ++kc)
    af[kc] = *(const bf16x8*)&sm[wv * 2176u + ln * 136u + (unsigned)kc * 32u + q * 8u];
  __syncthreads(); // af reads drained before Wt overwrites sm

  // ---- phase 3: per n-quarter: stage Wt (16 KB), MFMA, bias + GELU, nt-store --
#pragma unroll
  for (int qt = 0; qt < 4; ++qt) {
    const int nbase = qt * 64;
#pragma unroll
    for (int i2 = 0; i2 < 4; ++i2) {
      int slot = i2 * 256 + (int)tid; // 0..1023 = 64 rows x 16 k-units
      int n = slot >> 4, k8 = slot & 15;
      uint4 u = *(const uint4*)(Wt + (size_t)(nbase + n) * 128 + k8 * 8);
      *(uint4*)&sm[n * 136 + k8 * 8] = u;
    }
    __syncthreads();

    f32x4 acc[4];
#pragma unroll
    for (int f = 0; f < 4; ++f) acc[f] = (f32x4){0.f, 0.f, 0.f, 0.f};
#pragma unroll
    for (int kc = 0; kc < 4; ++kc) {
#pragma unroll
      for (int f = 0; f < 4; ++f) {
        // B[k=q*8+j][n=f*16+ln] contiguous in Wt[n][k]
        bf16x8 bf = *(const bf16x8*)&sm[(f * 16 + (int)ln) * 136 + kc * 32 + (int)q * 8];
        acc[f] = __builtin_amdgcn_mfma_f32_16x16x32_bf16(af[kc], bf, acc[f], 0, 0, 0);
      }
    }

    // Epilogue: C/D layout col = lane&15, row = quad*4 + reg (m89-verified).
    // out is write-once -> nontemporal (don't evict the x_bf gather set).
#pragma unroll
    for (int f = 0; f < 4; ++f) {
      int n = nbase + f * 16 + (int)ln;
      float bv = bias[n];
#pragma unroll
      for (int r = 0; r < 4; ++r) {
        size_t mrow = ((size_t)b << 14) + mbase + (wv << 4) + q * 4u + (unsigned)r;
        __builtin_nontemporal_store(gelu_exact(acc[f][r] + bv),
                                    &out[mrow * 256 + n]);
      }
    }
    __syncthreads(); // protect sm before next quarter's restage
  }
}

extern "C" void kernel_launch(void* const* d_in, const int* in_sizes, int n_in,
                              void* d_out, int out_size, void* d_ws, size_t ws_size,
                              hipStream_t stream) {
  const float* x      = (const float*)d_in[0];
  const unsigned* eid = (const unsigned*)d_in[1];
  const float* W      = (const float*)d_in[2];
  const float* bia    = (const float*)d_in[3];
  float* out          = (float*)d_out;
  unsigned* ws        = (unsigned*)d_ws;

  const unsigned short* Wt = (const unsigned short*)(ws + WT_OFF);

  // zero cnt[16384] + ovf_cnt (+pad)
  hipMemsetAsync(ws + CNT_OFF, 0, 16448 * sizeof(unsigned), stream);
  hipLaunchKernelGGL(k_prep, dim3(17536), dim3(256), 0, stream, x, eid, W, ws);
  hipLaunchKernelGGL(k_ag,   dim3(2048),  dim3(256), 0, stream,
                     (const uint4*)(ws + XBF_OFF), ws, Wt, bia, out);
}

// Round 7
// 312.944 us; speedup vs baseline: 1.0141x; 1.0141x over previous
//
#include <hip/hip_runtime.h>
#include <hip/hip_bf16.h>

// Problem constants (all powers of two -> index math is shifts/masks)
#define B_   8
#define N_   16384
#define C_   128
#define OUT_ 256
#define E_   262144

// ws word layout (uint32 offsets). ws_size ~537 MB, we use ~40 MB.
//   [0,        16384)    : cnt[row]; memset 0 -> per-row edge count (may exceed 64)
//   [16384,    16448)    : ovf_cnt (word 16384) + pad; memset covers it
//   [16448,    540736)   : overflow (row,col) pairs - correctness path only
//   [540736,   1589312)  : tab: fixed-capacity col table, 64 slots/row (16384*64)
//   [1589312,  1605696)  : Wt bf16 [n][k] transposed weights (256x128)
//   [1605696,  9994304)  : x_bf bf16 copy of x (B*N*C shorts)
#define CNT_OFF  0u
#define OVFC_OFF 16384u
#define OVF_OFF  16448u
#define TAB_OFF  540736u
#define WT_OFF   1589312u
#define XBF_OFF  1605696u

typedef __attribute__((ext_vector_type(8))) short bf16x8; // 8 bf16 = 4 VGPRs
typedef __attribute__((ext_vector_type(4))) float f32x4;

__device__ __forceinline__ unsigned short f2bf(float f) { // RNE, no NaN inputs
  unsigned u = __float_as_uint(f);
  u += 0x7FFFu + ((u >> 16) & 1u);
  return (unsigned short)(u >> 16);
}
__device__ __forceinline__ float gelu_exact(float v) {
  return 0.5f * v * (1.0f + erff(v * 0.70710678118654752f));
}
__device__ __forceinline__ unsigned umin_(unsigned a, unsigned b) {
  return a < b ? a : b;
}

// ------------- kernel 1: fused x->bf16 | direct edge-table build | Wt prep ------
// Fixed-capacity table (64 slots/row) built in ONE edge pass with atomic cursors
// (the gather needs the col SET, not order). Overflow rows (P ~ 1e-14 at
// Poisson(16)) spill (row,col) pairs to a global list replayed later -> correct
// for ANY input. Per-block dtype detect: odd u32 words are int64-highs (==0) or
// int32 index values (nonzero w.h.p.); 256 samples/block -> P(wrong) ~ 0.
__global__ __launch_bounds__(256) void k_prep(const float* __restrict__ x,
                                              const unsigned* __restrict__ eidx,
                                              const float* __restrict__ W,
                                              unsigned* __restrict__ ws) {
  const unsigned bid = blockIdx.x, tid = threadIdx.x;
  if (bid < 16384u) { // ---- x fp32 -> bf16 packed (4,194,304 float4 slots)
    unsigned i = bid * 256u + tid;
    float4 v = ((const float4*)x)[i];
    uint2 o;
    o.x = (unsigned)f2bf(v.x) | ((unsigned)f2bf(v.y) << 16);
    o.y = (unsigned)f2bf(v.z) | ((unsigned)f2bf(v.w) << 16);
    ((uint2*)(ws + XBF_OFF))[i] = o;
  } else if (bid < 17408u) { // ---- edge-table build, one edge per thread
    __shared__ int flag32;
    if (tid == 0) flag32 = 0;
    __syncthreads();
    unsigned e = (bid - 16384u) * 256u + tid; // 0..262143
    if (eidx[2u * e + 1u] != 0u) flag32 = 1;  // benign race
    __syncthreads();
    int row, col;
    if (flag32) {
      row = (int)eidx[e];
      col = (int)eidx[e + E_];
    } else {
      const long long* p = (const long long*)eidx;
      row = (int)p[e];
      col = (int)p[e + E_];
    }
    unsigned pos = atomicAdd(ws + CNT_OFF + (unsigned)row, 1u);
    if (pos < 64u) {
      ws[TAB_OFF + ((unsigned)row << 6) + pos] = (unsigned)col;
    } else { // correctness-only spill
      unsigned o = atomicAdd(ws + OVFC_OFF, 1u);
      ws[OVF_OFF + 2u * o]      = (unsigned)row;
      ws[OVF_OFF + 2u * o + 1u] = (unsigned)col;
    }
  } else { // ---- W fp32 -> bf16 transposed (128 blocks)
    unsigned t = (bid - 17408u) * 256u + tid; // 0..32767
    unsigned n = t >> 7, k = t & 127u;
    ((unsigned short*)(ws + WT_OFF))[n * 128u + k] = f2bf(W[k * 256u + n]);
  }
}

// -------- kernel 2: FUSED gather-max -> (LDS transpose) -> MFMA gemm -> GELU ----
// R6 lesson (counter-proven): __launch_bounds__(256,8) forced a 64-reg TOTAL
// budget (VGPR+AGPR unified on gfx950) -> 32 arch VGPRs -> scratch spill
// (+70 MB FETCH, +89 MB WRITE). R7 removes the bound; natural allocation is
// ~64 VGPR + ~16 AGPR (R5-proven spill-free), giving ~6 waves/SIMD with the
// 17408 B LDS (9 blocks/CU LDS-cap). Kept from R6:
//   * LDS 17408 B: Wt staged in n-QUARTERS -> occupancy not LDS-capped at 4.
//   * nontemporal OUT stores + TAB/OVF loads (streams bypass L2; x_bf stays).
//   * per-row trip guards; cnt[] hoisted to one load/wave.
// EXEC discipline (R1 bug): every __shfl under wave-uniform control flow.
// Max trick: fmax on raw u32 (hi channel; garbage low mantissa can't flip a
// bf16-level compare) and on u<<16 (lo channel, exact). batch = blockIdx&7 ->
// per-XCD 4 MB x_bf slice under round-robin dispatch.
__global__ __launch_bounds__(256) void k_ag(const uint4* __restrict__ xbf4,
                                            const unsigned* __restrict__ ws,
                                            const unsigned short* __restrict__ Wt,
                                            const float* __restrict__ bias,
                                            float* __restrict__ out) {
  __shared__ unsigned short sm[8704]; // 17408 B: 4 trans strips / one Wt quarter
  const unsigned bi = blockIdx.x;          // 2048 = 256 m-tiles x 8 batches
  const unsigned b  = bi & 7u;
  const unsigned mbase = (bi >> 3) << 6;   // 64-row m-tile
  const unsigned tid = threadIdx.x;
  const unsigned wv = tid >> 6;            // wave id: rows [wv*16, wv*16+16)
  const unsigned lane = tid & 63u;
  const unsigned g  = lane >> 4;           // edge subgroup 0..3
  const unsigned ln = lane & 15u;          // uint4 slot within a 128-ch row
  const uint4* xb = xbf4 + ((size_t)b << 18); // rows stride 16 uint4
  const unsigned wbase = mbase + (wv << 4);

  // one load covers all 16 row degrees for this wave (lanes 16+ hold dups)
  const unsigned cnt16 = ws[CNT_OFF + wbase + ln];

#define MAXU4(U, ml, mh)                                                    \
  mh[0] = fmaxf(mh[0], __uint_as_float((U).x));                             \
  ml[0] = fmaxf(ml[0], __uint_as_float((U).x << 16));                       \
  mh[1] = fmaxf(mh[1], __uint_as_float((U).y));                             \
  ml[1] = fmaxf(ml[1], __uint_as_float((U).y << 16));                       \
  mh[2] = fmaxf(mh[2], __uint_as_float((U).z));                             \
  ml[2] = fmaxf(ml[2], __uint_as_float((U).z << 16));                       \
  mh[3] = fmaxf(mh[3], __uint_as_float((U).w));                             \
  ml[3] = fmaxf(ml[3], __uint_as_float((U).w << 16));

  // ---- phase 1: gather-max, 2 rows per iteration, per-row trip guards ----
  for (unsigned i = 0u; i < 16u; i += 2u) {
    const unsigned ra = wbase + i, rb = ra + 1u;
    const unsigned dega = (unsigned)__shfl((int)cnt16, (int)i);        // uniform
    const unsigned degb = (unsigned)__shfl((int)cnt16, (int)(i + 1u)); // uniform
    const unsigned d64a = dega < 64u ? dega : 64u;
    const unsigned d64b = degb < 64u ? degb : 64u;
    const unsigned dm1a = d64a - 1u; // used only when d64a > 0
    const unsigned dm1b = d64b - 1u;
    // tab: read-once stream, shared by all 8 XCDs -> bypass L2 (L3 serves it)
    const unsigned cprea = __builtin_nontemporal_load(ws + TAB_OFF + (ra << 6) + lane);
    const unsigned cpreb = __builtin_nontemporal_load(ws + TAB_OFF + (rb << 6) + lane);
    const uint4 xwa = xb[((size_t)ra << 4) + ln]; // own-row x (epilogue operand)
    const uint4 xwb = xb[((size_t)rb << 4) + ln];

    float mloa[4], mhia[4], mlob[4], mhib[4];
#pragma unroll
    for (int r = 0; r < 4; ++r) {
      mloa[r] = -INFINITY; mhia[r] = -INFINITY;
      mlob[r] = -INFINITY; mhib[r] = -INFINITY;
    }

    const unsigned mx = d64a > d64b ? d64a : d64b;
    for (unsigned t = 0u; t < mx; t += 16u) {
      if (t < d64a) { // wave-uniform -> full-EXEC shuffles inside
        unsigned ca[4];
#pragma unroll
        for (int k = 0; k < 4; ++k)
          ca[k] = (unsigned)__shfl((int)cprea,
                                   (int)umin_(t + 4u * (unsigned)k + g, dm1a));
        uint4 ua[4];
#pragma unroll
        for (int k = 0; k < 4; ++k) ua[k] = xb[((size_t)ca[k] << 4) + ln];
#pragma unroll
        for (int k = 0; k < 4; ++k) { MAXU4(ua[k], mloa, mhia) }
      }
      if (t < d64b) { // wave-uniform
        unsigned cb[4];
#pragma unroll
        for (int k = 0; k < 4; ++k)
          cb[k] = (unsigned)__shfl((int)cpreb,
                                   (int)umin_(t + 4u * (unsigned)k + g, dm1b));
        uint4 ub[4];
#pragma unroll
        for (int k = 0; k < 4; ++k) ub[k] = xb[((size_t)cb[k] << 4) + ln];
#pragma unroll
        for (int k = 0; k < 4; ++k) { MAXU4(ub[k], mlob, mhib) }
      }
    }
    if ((dega > 64u) | (degb > 64u)) { // overflow replay: shuffle-free
      unsigned no = ws[OVFC_OFF];
      for (unsigned k2 = g; k2 < no; k2 += 4u) {
        unsigned rr = __builtin_nontemporal_load(ws + OVF_OFF + 2u * k2);
        if (rr == ra) {
          uint4 u = xb[((size_t)ws[OVF_OFF + 2u * k2 + 1u] << 4) + ln];
          MAXU4(u, mloa, mhia)
        } else if (rr == rb) {
          uint4 u = xb[((size_t)ws[OVF_OFF + 2u * k2 + 1u] << 4) + ln];
          MAXU4(u, mlob, mhib)
        }
      }
    }

    // reduce across the 4 edge-groups (full EXEC, reconverged)
#pragma unroll
    for (int r = 0; r < 4; ++r) {
      mloa[r] = fmaxf(mloa[r], __shfl_xor(mloa[r], 16, 64));
      mhia[r] = fmaxf(mhia[r], __shfl_xor(mhia[r], 16, 64));
      mloa[r] = fmaxf(mloa[r], __shfl_xor(mloa[r], 32, 64));
      mhia[r] = fmaxf(mhia[r], __shfl_xor(mhia[r], 32, 64));
      mlob[r] = fmaxf(mlob[r], __shfl_xor(mlob[r], 16, 64));
      mhib[r] = fmaxf(mhib[r], __shfl_xor(mhib[r], 16, 64));
      mlob[r] = fmaxf(mlob[r], __shfl_xor(mlob[r], 32, 64));
      mhib[r] = fmaxf(mhib[r], __shfl_xor(mhib[r], 32, 64));
    }

    if (g == 0u) { // write both rows' aggr bf16 to this wave's LDS strip
      const bool hasa = (dega != 0u), hasb = (degb != 0u);
      unsigned xva[4] = {xwa.x, xwa.y, xwa.z, xwa.w};
      unsigned xvb[4] = {xwb.x, xwb.y, xwb.z, xwb.w};
      unsigned oxa[4], oxb[4];
#pragma unroll
      for (int r = 0; r < 4; ++r) {
        float vloa = hasa ? mloa[r] : 0.0f;
        float vhia = hasa ? __uint_as_float(__float_as_uint(mhia[r]) & 0xFFFF0000u) : 0.0f;
        oxa[r] = (unsigned)f2bf(vloa - __uint_as_float(xva[r] << 16)) |
                 ((unsigned)f2bf(vhia - __uint_as_float(xva[r] & 0xFFFF0000u)) << 16);
        float vlob = hasb ? mlob[r] : 0.0f;
        float vhib = hasb ? __uint_as_float(__float_as_uint(mhib[r]) & 0xFFFF0000u) : 0.0f;
        oxb[r] = (unsigned)f2bf(vlob - __uint_as_float(xvb[r] << 16)) |
                 ((unsigned)f2bf(vhib - __uint_as_float(xvb[r] & 0xFFFF0000u)) << 16);
      }
      uint4 oa = {oxa[0], oxa[1], oxa[2], oxa[3]};
      uint4 ob = {oxb[0], oxb[1], oxb[2], oxb[3]};
      *(uint4*)&sm[wv * 2176u + i * 136u + ln * 8u]        = oa;
      *(uint4*)&sm[wv * 2176u + (i + 1u) * 136u + ln * 8u] = ob;
    }
  }
#undef MAXU4

  __syncthreads(); // trans strips complete (also orders vs af reads)

  // ---- phase 2: A-fragments from LDS. lane(ln,q): A[m=ln][ch=kc*32+q*8..+8]
  const unsigned q = g;
  bf16x8 af[4];
#pragma unroll
  for (int kc = 0; kc < 4; ++kc)
    af[kc] = *(const bf16x8*)&sm[wv * 2176u + ln * 136u + (unsigned)kc * 32u + q * 8u];
  __syncthreads(); // af reads drained before Wt overwrites sm

  // ---- phase 3: per n-quarter: stage Wt (16 KB), MFMA, bias + GELU, nt-store --
#pragma unroll
  for (int qt = 0; qt < 4; ++qt) {
    const int nbase = qt * 64;
#pragma unroll
    for (int i2 = 0; i2 < 4; ++i2) {
      int slot = i2 * 256 + (int)tid; // 0..1023 = 64 rows x 16 k-units
      int n = slot >> 4, k8 = slot & 15;
      uint4 u = *(const uint4*)(Wt + (size_t)(nbase + n) * 128 + k8 * 8);
      *(uint4*)&sm[n * 136 + k8 * 8] = u;
    }
    __syncthreads();

    f32x4 acc[4];
#pragma unroll
    for (int f = 0; f < 4; ++f) acc[f] = (f32x4){0.f, 0.f, 0.f, 0.f};
#pragma unroll
    for (int kc = 0; kc < 4; ++kc) {
#pragma unroll
      for (int f = 0; f < 4; ++f) {
        // B[k=q*8+j][n=f*16+ln] contiguous in Wt[n][k]
        bf16x8 bf = *(const bf16x8*)&sm[(f * 16 + (int)ln) * 136 + kc * 32 + (int)q * 8];
        acc[f] = __builtin_amdgcn_mfma_f32_16x16x32_bf16(af[kc], bf, acc[f], 0, 0, 0);
      }
    }

    // Epilogue: C/D layout col = lane&15, row = quad*4 + reg (m89-verified).
    // out is write-once -> nontemporal (don't evict the x_bf gather set).
#pragma unroll
    for (int f = 0; f < 4; ++f) {
      int n = nbase + f * 16 + (int)ln;
      float bv = bias[n];
#pragma unroll
      for (int r = 0; r < 4; ++r) {
        size_t mrow = ((size_t)b << 14) + mbase + (wv << 4) + q * 4u + (unsigned)r;
        __builtin_nontemporal_store(gelu_exact(acc[f][r] + bv),
                                    &out[mrow * 256 + n]);
      }
    }
    __syncthreads(); // protect sm before next quarter's restage
  }
}

extern "C" void kernel_launch(void* const* d_in, const int* in_sizes, int n_in,
                              void* d_out, int out_size, void* d_ws, size_t ws_size,
                              hipStream_t stream) {
  const float* x      = (const float*)d_in[0];
  const unsigned* eid = (const unsigned*)d_in[1];
  const float* W      = (const float*)d_in[2];
  const float* bia    = (const float*)d_in[3];
  float* out          = (float*)d_out;
  unsigned* ws        = (unsigned*)d_ws;

  const unsigned short* Wt = (const unsigned short*)(ws + WT_OFF);

  // zero cnt[16384] + ovf_cnt (+pad)
  hipMemsetAsync(ws + CNT_OFF, 0, 16448 * sizeof(unsigned), stream);
  hipLaunchKernelGGL(k_prep, dim3(17536), dim3(256), 0, stream, x, eid, W, ws);
  hipLaunchKernelGGL(k_ag,   dim3(2048),  dim3(256), 0, stream,
                     (const uint4*)(ws + XBF_OFF), ws, Wt, bia, out);
}

// Round 9
// 312.120 us; speedup vs baseline: 1.0168x; 1.0026x over previous
//
#include <hip/hip_runtime.h>
#include <hip/hip_bf16.h>

// Problem constants (all powers of two -> index math is shifts/masks)
#define B_   8
#define N_   16384
#define C_   128
#define OUT_ 256
#define E_   262144

// ws word layout (uint32 offsets). ws_size ~537 MB, we use ~40 MB.
//   [0,        16384)    : cnt[row]; memset 0 -> per-row edge count (may exceed 64)
//   [16384,    16448)    : ovf_cnt (word 16384) + pad; memset covers it
//   [16448,    540736)   : overflow (row,col) pairs - correctness path only
//   [540736,   1589312)  : tab: fixed-capacity col table, 64 slots/row (16384*64)
//   [1589312,  1605696)  : Wt bf16 [n][k] transposed weights (256x128)
//   [1605696,  9994304)  : x_bf bf16 copy of x (B*N*C shorts)
#define CNT_OFF  0u
#define OVFC_OFF 16384u
#define OVF_OFF  16448u
#define TAB_OFF  540736u
#define WT_OFF   1589312u
#define XBF_OFF  1605696u

typedef __attribute__((ext_vector_type(8))) short bf16x8; // 8 bf16 = 4 VGPRs
typedef __attribute__((ext_vector_type(4))) float f32x4;

__device__ __forceinline__ unsigned short f2bf(float f) { // RNE, no NaN inputs
  unsigned u = __float_as_uint(f);
  u += 0x7FFFu + ((u >> 16) & 1u);
  return (unsigned short)(u >> 16);
}
__device__ __forceinline__ float gelu_exact(float v) {
  return 0.5f * v * (1.0f + erff(v * 0.70710678118654752f));
}
__device__ __forceinline__ unsigned umin_(unsigned a, unsigned b) {
  return a < b ? a : b;
}

// ------------- kernel 1: fused x->bf16 | direct edge-table build | Wt prep ------
// Fixed-capacity table (64 slots/row) built in ONE edge pass with atomic cursors
// (the gather needs the col SET, not order). Overflow rows (P ~ 1e-14 at
// Poisson(16)) spill (row,col) pairs to a global list replayed later -> correct
// for ANY input. Per-block dtype detect: odd u32 words are int64-highs (==0) or
// int32 index values (nonzero w.h.p.); 256 samples/block -> P(wrong) ~ 0.
__global__ __launch_bounds__(256) void k_prep(const float* __restrict__ x,
                                              const unsigned* __restrict__ eidx,
                                              const float* __restrict__ W,
                                              unsigned* __restrict__ ws) {
  const unsigned bid = blockIdx.x, tid = threadIdx.x;
  if (bid < 16384u) { // ---- x fp32 -> bf16 packed (4,194,304 float4 slots)
    unsigned i = bid * 256u + tid;
    float4 v = ((const float4*)x)[i];
    uint2 o;
    o.x = (unsigned)f2bf(v.x) | ((unsigned)f2bf(v.y) << 16);
    o.y = (unsigned)f2bf(v.z) | ((unsigned)f2bf(v.w) << 16);
    ((uint2*)(ws + XBF_OFF))[i] = o;
  } else if (bid < 17408u) { // ---- edge-table build, one edge per thread
    __shared__ int flag32;
    if (tid == 0) flag32 = 0;
    __syncthreads();
    unsigned e = (bid - 16384u) * 256u + tid; // 0..262143
    if (eidx[2u * e + 1u] != 0u) flag32 = 1;  // benign race
    __syncthreads();
    int row, col;
    if (flag32) {
      row = (int)eidx[e];
      col = (int)eidx[e + E_];
    } else {
      const long long* p = (const long long*)eidx;
      row = (int)p[e];
      col = (int)p[e + E_];
    }
    unsigned pos = atomicAdd(ws + CNT_OFF + (unsigned)row, 1u);
    if (pos < 64u) {
      ws[TAB_OFF + ((unsigned)row << 6) + pos] = (unsigned)col;
    } else { // correctness-only spill
      unsigned o = atomicAdd(ws + OVFC_OFF, 1u);
      ws[OVF_OFF + 2u * o]      = (unsigned)row;
      ws[OVF_OFF + 2u * o + 1u] = (unsigned)col;
    }
  } else { // ---- W fp32 -> bf16 transposed (128 blocks)
    unsigned t = (bid - 17408u) * 256u + tid; // 0..32767
    unsigned n = t >> 7, k = t & 127u;
    ((unsigned short*)(ws + WT_OFF))[n * 128u + k] = f2bf(W[k * 256u + n]);
  }
}

// -------- kernel 2: FUSED gather-max -> (LDS transpose) -> MFMA gemm -> GELU ----
// Register-budget history (counter-proven):
//   R5 (256,4): 64 VGPR, WRITE=132=out exactly -> SPILL-FREE.
//   R6 (256,8): 32 VGPR -> +70/+89 MB spill traffic.
//   R7 (none):  56 VGPR -> +37 MB spill stores, spill chains in gather loop.
// => phase 1 needs ~64-80 regs; ONLY the 128-reg budget of (256,4) is known
// spill-free. R8 = R7 + __launch_bounds__(256,4): first build combining
//   * spill-free regs (R5-proven)
//   * 17408 B LDS (R6-proven): regs cap at ~80 total -> 6 blocks/CU (24 w/CU),
//     +50% TLP over R5's LDS-capped 4 blocks/CU
//   * nt OUT stores + nt TAB/OVF loads (R7-proven: FETCH 155->48 MB)
// EXEC discipline (R1 bug): every __shfl under wave-uniform control flow.
// Max trick: fmax on raw u32 (hi channel; garbage low mantissa can't flip a
// bf16-level compare) and on u<<16 (lo channel, exact). batch = blockIdx&7 ->
// per-XCD 4 MB x_bf slice under round-robin dispatch.
__global__ __launch_bounds__(256, 4) void k_ag(const uint4* __restrict__ xbf4,
                                               const unsigned* __restrict__ ws,
                                               const unsigned short* __restrict__ Wt,
                                               const float* __restrict__ bias,
                                               float* __restrict__ out) {
  __shared__ unsigned short sm[8704]; // 17408 B: 4 trans strips / one Wt quarter
  const unsigned bi = blockIdx.x;          // 2048 = 256 m-tiles x 8 batches
  const unsigned b  = bi & 7u;
  const unsigned mbase = (bi >> 3) << 6;   // 64-row m-tile
  const unsigned tid = threadIdx.x;
  const unsigned wv = tid >> 6;            // wave id: rows [wv*16, wv*16+16)
  const unsigned lane = tid & 63u;
  const unsigned g  = lane >> 4;           // edge subgroup 0..3
  const unsigned ln = lane & 15u;          // uint4 slot within a 128-ch row
  const uint4* xb = xbf4 + ((size_t)b << 18); // rows stride 16 uint4
  const unsigned wbase = mbase + (wv << 4);

  // one load covers all 16 row degrees for this wave (lanes 16+ hold dups)
  const unsigned cnt16 = ws[CNT_OFF + wbase + ln];

#define MAXU4(U, ml, mh)                                                    \
  mh[0] = fmaxf(mh[0], __uint_as_float((U).x));                             \
  ml[0] = fmaxf(ml[0], __uint_as_float((U).x << 16));                       \
  mh[1] = fmaxf(mh[1], __uint_as_float((U).y));                             \
  ml[1] = fmaxf(ml[1], __uint_as_float((U).y << 16));                       \
  mh[2] = fmaxf(mh[2], __uint_as_float((U).z));                             \
  ml[2] = fmaxf(ml[2], __uint_as_float((U).z << 16));                       \
  mh[3] = fmaxf(mh[3], __uint_as_float((U).w));                             \
  ml[3] = fmaxf(ml[3], __uint_as_float((U).w << 16));

  // ---- phase 1: gather-max, 2 rows per iteration, per-row trip guards ----
  for (unsigned i = 0u; i < 16u; i += 2u) {
    const unsigned ra = wbase + i, rb = ra + 1u;
    const unsigned dega = (unsigned)__shfl((int)cnt16, (int)i);        // uniform
    const unsigned degb = (unsigned)__shfl((int)cnt16, (int)(i + 1u)); // uniform
    const unsigned d64a = dega < 64u ? dega : 64u;
    const unsigned d64b = degb < 64u ? degb : 64u;
    const unsigned dm1a = d64a - 1u; // used only when d64a > 0
    const unsigned dm1b = d64b - 1u;
    // tab: read-once stream, shared by all 8 XCDs -> bypass L2 (L3 serves it)
    const unsigned cprea = __builtin_nontemporal_load(ws + TAB_OFF + (ra << 6) + lane);
    const unsigned cpreb = __builtin_nontemporal_load(ws + TAB_OFF + (rb << 6) + lane);
    const uint4 xwa = xb[((size_t)ra << 4) + ln]; // own-row x (epilogue operand)
    const uint4 xwb = xb[((size_t)rb << 4) + ln];

    float mloa[4], mhia[4], mlob[4], mhib[4];
#pragma unroll
    for (int r = 0; r < 4; ++r) {
      mloa[r] = -INFINITY; mhia[r] = -INFINITY;
      mlob[r] = -INFINITY; mhib[r] = -INFINITY;
    }

    const unsigned mx = d64a > d64b ? d64a : d64b;
    for (unsigned t = 0u; t < mx; t += 16u) {
      if (t < d64a) { // wave-uniform -> full-EXEC shuffles inside
        unsigned ca[4];
#pragma unroll
        for (int k = 0; k < 4; ++k)
          ca[k] = (unsigned)__shfl((int)cprea,
                                   (int)umin_(t + 4u * (unsigned)k + g, dm1a));
        uint4 ua[4];
#pragma unroll
        for (int k = 0; k < 4; ++k) ua[k] = xb[((size_t)ca[k] << 4) + ln];
#pragma unroll
        for (int k = 0; k < 4; ++k) { MAXU4(ua[k], mloa, mhia) }
      }
      if (t < d64b) { // wave-uniform
        unsigned cb[4];
#pragma unroll
        for (int k = 0; k < 4; ++k)
          cb[k] = (unsigned)__shfl((int)cpreb,
                                   (int)umin_(t + 4u * (unsigned)k + g, dm1b));
        uint4 ub[4];
#pragma unroll
        for (int k = 0; k < 4; ++k) ub[k] = xb[((size_t)cb[k] << 4) + ln];
#pragma unroll
        for (int k = 0; k < 4; ++k) { MAXU4(ub[k], mlob, mhib) }
      }
    }
    if ((dega > 64u) | (degb > 64u)) { // overflow replay: shuffle-free
      unsigned no = ws[OVFC_OFF];
      for (unsigned k2 = g; k2 < no; k2 += 4u) {
        unsigned rr = __builtin_nontemporal_load(ws + OVF_OFF + 2u * k2);
        if (rr == ra) {
          uint4 u = xb[((size_t)ws[OVF_OFF + 2u * k2 + 1u] << 4) + ln];
          MAXU4(u, mloa, mhia)
        } else if (rr == rb) {
          uint4 u = xb[((size_t)ws[OVF_OFF + 2u * k2 + 1u] << 4) + ln];
          MAXU4(u, mlob, mhib)
        }
      }
    }

    // reduce across the 4 edge-groups (full EXEC, reconverged)
#pragma unroll
    for (int r = 0; r < 4; ++r) {
      mloa[r] = fmaxf(mloa[r], __shfl_xor(mloa[r], 16, 64));
      mhia[r] = fmaxf(mhia[r], __shfl_xor(mhia[r], 16, 64));
      mloa[r] = fmaxf(mloa[r], __shfl_xor(mloa[r], 32, 64));
      mhia[r] = fmaxf(mhia[r], __shfl_xor(mhia[r], 32, 64));
      mlob[r] = fmaxf(mlob[r], __shfl_xor(mlob[r], 16, 64));
      mhib[r] = fmaxf(mhib[r], __shfl_xor(mhib[r], 16, 64));
      mlob[r] = fmaxf(mlob[r], __shfl_xor(mlob[r], 32, 64));
      mhib[r] = fmaxf(mhib[r], __shfl_xor(mhib[r], 32, 64));
    }

    if (g == 0u) { // write both rows' aggr bf16 to this wave's LDS strip
      const bool hasa = (dega != 0u), hasb = (degb != 0u);
      unsigned xva[4] = {xwa.x, xwa.y, xwa.z, xwa.w};
      unsigned xvb[4] = {xwb.x, xwb.y, xwb.z, xwb.w};
      unsigned oxa[4], oxb[4];
#pragma unroll
      for (int r = 0; r < 4; ++r) {
        float vloa = hasa ? mloa[r] : 0.0f;
        float vhia = hasa ? __uint_as_float(__float_as_uint(mhia[r]) & 0xFFFF0000u) : 0.0f;
        oxa[r] = (unsigned)f2bf(vloa - __uint_as_float(xva[r] << 16)) |
                 ((unsigned)f2bf(vhia - __uint_as_float(xva[r] & 0xFFFF0000u)) << 16);
        float vlob = hasb ? mlob[r] : 0.0f;
        float vhib = hasb ? __uint_as_float(__float_as_uint(mhib[r]) & 0xFFFF0000u) : 0.0f;
        oxb[r] = (unsigned)f2bf(vlob - __uint_as_float(xvb[r] << 16)) |
                 ((unsigned)f2bf(vhib - __uint_as_float(xvb[r] & 0xFFFF0000u)) << 16);
      }
      uint4 oa = {oxa[0], oxa[1], oxa[2], oxa[3]};
      uint4 ob = {oxb[0], oxb[1], oxb[2], oxb[3]};
      *(uint4*)&sm[wv * 2176u + i * 136u + ln * 8u]        = oa;
      *(uint4*)&sm[wv * 2176u + (i + 1u) * 136u + ln * 8u] = ob;
    }
  }
#undef MAXU4

  __syncthreads(); // trans strips complete (also orders vs af reads)

  // ---- phase 2: A-fragments from LDS. lane(ln,q): A[m=ln][ch=kc*32+q*8..+8]
  const unsigned q = g;
  bf16x8 af[4];
#pragma unroll
  for (int kc = 0; kc < 4; ++kc)
    af[kc] = *(const bf16x8*)&sm[wv * 2176u + ln * 136u + (unsigned)kc * 32u + q * 8u];
  __syncthreads(); // af reads drained before Wt overwrites sm

  // ---- phase 3: per n-quarter: stage Wt (16 KB), MFMA, bias + GELU, nt-store --
#pragma unroll
  for (int qt = 0; qt < 4; ++qt) {
    const int nbase = qt * 64;
#pragma unroll
    for (int i2 = 0; i2 < 4; ++i2) {
      int slot = i2 * 256 + (int)tid; // 0..1023 = 64 rows x 16 k-units
      int n = slot >> 4, k8 = slot & 15;
      uint4 u = *(const uint4*)(Wt + (size_t)(nbase + n) * 128 + k8 * 8);
      *(uint4*)&sm[n * 136 + k8 * 8] = u;
    }
    __syncthreads();

    f32x4 acc[4];
#pragma unroll
    for (int f = 0; f < 4; ++f) acc[f] = (f32x4){0.f, 0.f, 0.f, 0.f};
#pragma unroll
    for (int kc = 0; kc < 4; ++kc) {
#pragma unroll
      for (int f = 0; f < 4; ++f) {
        // B[k=q*8+j][n=f*16+ln] contiguous in Wt[n][k]
        bf16x8 bf = *(const bf16x8*)&sm[(f * 16 + (int)ln) * 136 + kc * 32 + (int)q * 8];
        acc[f] = __builtin_amdgcn_mfma_f32_16x16x32_bf16(af[kc], bf, acc[f], 0, 0, 0);
      }
    }

    // Epilogue: C/D layout col = lane&15, row = quad*4 + reg (m89-verified).
    // out is write-once -> nontemporal (don't evict the x_bf gather set).
#pragma unroll
    for (int f = 0; f < 4; ++f) {
      int n = nbase + f * 16 + (int)ln;
      float bv = bias[n];
#pragma unroll
      for (int r = 0; r < 4; ++r) {
        size_t mrow = ((size_t)b << 14) + mbase + (wv << 4) + q * 4u + (unsigned)r;
        __builtin_nontemporal_store(gelu_exact(acc[f][r] + bv),
                                    &out[mrow * 256 + n]);
      }
    }
    __syncthreads(); // protect sm before next quarter's restage
  }
}

extern "C" void kernel_launch(void* const* d_in, const int* in_sizes, int n_in,
                              void* d_out, int out_size, void* d_ws, size_t ws_size,
                              hipStream_t stream) {
  const float* x      = (const float*)d_in[0];
  const unsigned* eid = (const unsigned*)d_in[1];
  const float* W      = (const float*)d_in[2];
  const float* bia    = (const float*)d_in[3];
  float* out          = (float*)d_out;
  unsigned* ws        = (unsigned*)d_ws;

  const unsigned short* Wt = (const unsigned short*)(ws + WT_OFF);

  // zero cnt[16384] + ovf_cnt (+pad)
  hipMemsetAsync(ws + CNT_OFF, 0, 16448 * sizeof(unsigned), stream);
  hipLaunchKernelGGL(k_prep, dim3(17536), dim3(256), 0, stream, x, eid, W, ws);
  hipLaunchKernelGGL(k_ag,   dim3(2048),  dim3(256), 0, stream,
                     (const uint4*)(ws + XBF_OFF), ws, Wt, bia, out);
}